// Round 20
// baseline (7564.266 us; speedup 1.0000x reference)
//
#include <hip/hip_runtime.h>

typedef __attribute__((ext_vector_type(8))) short short8;
typedef __attribute__((ext_vector_type(4))) float f32x4;

// Workspace layout (bytes)
#define WS_XB     0ull          // x in bf16: [64][512][512]            33,554,432 B
#define WS_W0T    33554432ull   // layer0 weights^T fused: [4096][1536] 12,582,912 B
#define WS_W1T    46137344ull   // layer1 weights^T fused: [4096][2048] 16,777,216 B
#define WS_RING0  62914560ull   // h0 ring: [32][64][1024] bf16           4,194,304 B
#define WS_RING1  67108864ull   // h1 ring: [32][64][1024] bf16           4,194,304 B
#define WS_BAR    71303168ull   // barrier words (<=8192 B used)
#define SLOT_ELEMS 65536        // 64 batches x 1024 units per ring slot
#define SLOT_BYTES 131072

// Split per-layer barrier, 2 blocks/CU edition: 256 blocks/layer = 16 groups
// x 16 blocks. Laws (R9/R10/R17): <=16 same-line RMWs/episode, <=2 RMW
// writers per poll line, single-u64-load polls, fan-out across lines.
//   ARR0(g)=g*16 (g<16), ARR1(g)=256+g*16, ROOT0=512, ROOT1=528,
//   POLL0(g)=544+g*16: word0=rel0, word1=mir1
//   POLL1(g)=800+g*16: word0=rel1, word1=mir0
#define ARR0(g)  ((g) * 16)
#define ARR1(g)  (256 + (g) * 16)
#define ROOT0    512
#define ROOT1    528
#define POLL0(g) (544 + (g) * 16)
#define POLL1(g) (800 + (g) * 16)

__device__ __forceinline__ unsigned short f2bf(float f) {
  unsigned u = __float_as_uint(f);
  u += 0x7FFFu + ((u >> 16) & 1u);   // round-to-nearest-even
  return (unsigned short)(u >> 16);
}

__device__ __forceinline__ float sigm(float x) { return 1.0f / (1.0f + __expf(-x)); }

// ---- sentinel: "persistent kernel never ran" (absmax ~1e6) marker ----
__global__ void sentinel_kernel(float* out) { out[0] = 1.0e6f; }

// ---- prep: fp32 -> bf16 copy of x (4 elems/thread) ----
__global__ void convert_x_kernel(const float* __restrict__ x, unsigned short* __restrict__ xb) {
  int i = blockIdx.x * 256 + threadIdx.x;
  const float4 v = ((const float4*)x)[i];
  unsigned long long pack = (unsigned long long)f2bf(v.x)
                          | ((unsigned long long)f2bf(v.y) << 16)
                          | ((unsigned long long)f2bf(v.z) << 32)
                          | ((unsigned long long)f2bf(v.w) << 48);
  ((unsigned long long*)xb)[i] = pack;
}

// ---- prep: transpose [K][4096] fp32 (Wx stacked over Wh) -> [4096 perm][Ktot] bf16 ----
// dst row r = unit*4 + gate: each block's 16 rows (4 units) are contiguous.
__global__ void transpose_weights_kernel(const float* __restrict__ wx, const float* __restrict__ wh,
                                         unsigned short* __restrict__ dst, int Kx, int Ktot) {
  __shared__ float tile[32][33];
  const int k0 = blockIdx.x * 32, n0 = blockIdx.y * 32;
  const int tx = threadIdx.x, ty = threadIdx.y;
#pragma unroll
  for (int i = 0; i < 4; ++i) {
    int k = k0 + ty + i * 8;
    tile[ty + i * 8][tx] = (k < Kx) ? wx[(size_t)k * 4096 + n0 + tx]
                                    : wh[(size_t)(k - Kx) * 4096 + n0 + tx];
  }
  __syncthreads();
#pragma unroll
  for (int i = 0; i < 4; ++i) {
    int n = n0 + ty + i * 8;
    int r = (n & 1023) * 4 + (n >> 10);
    dst[(size_t)r * Ktot + k0 + tx] = f2bf(tile[tx][ty + i * 8]);
  }
}

// ---- per-step MFMA micro-kernel: pinned 4-slot pipeline, ONE 16-row A-tile ----
template<int N1, int NBLK>
__device__ __forceinline__ void lstm_step_mfma(int a0b,
    const unsigned short* __restrict__ r1p, const unsigned short* __restrict__ r2p,
    f32x4& acc0)
{
  extern __shared__ unsigned short lds[];
  short8 buf[4][8];

  auto loadB = [&](int slot, int blk) {
    const unsigned short* p = (blk < N1) ? (r1p + blk * 256) : (r2p + (blk - N1) * 256);
#pragma unroll
    for (int j = 0; j < 8; ++j) buf[slot][j] = *(const short8*)(p + j * 32);
  };
  auto compute8 = [&](int slot, int kg) {
#pragma unroll
    for (int j = 0; j < 8; ++j) {
      const int ko = kg + j * 32;
      short8 a0 = *(const short8*)&lds[a0b + ko];
      acc0 = __builtin_amdgcn_mfma_f32_16x16x32_bf16(a0, buf[slot][j], acc0, 0, 0, 0);
    }
  };

  loadB(0, 0); loadB(1, 1); loadB(2, 2); loadB(3, 3);
  __builtin_amdgcn_sched_barrier(0);            // all 4 blocks issued before any compute
#pragma unroll
  for (int bp = 0; bp < NBLK; ++bp) {
    compute8(bp & 3, bp * 256);                 // consume block bp
    if (bp + 4 < NBLK) loadB(bp & 3, bp + 4);   // refill the freed slot
    __builtin_amdgcn_sched_barrier(0);          // refill may not sink into later iters
  }
}

// ---- persistent fused 2-layer LSTM, 2 blocks/CU (TLP sync-hiding) ----
// 512 WGs x 256 threads. WGs [0,256): layer0; [256,512): layer1. Each block
// owns 4 units (16 gate-rows, ONE MFMA A-tile); LDS 16 x KPAD x 2B = 65.8KB
// -> two blocks co-resident per CU. While one block spins in the barrier,
// its CU-mate computes: the sync window (7.5us/step single-occupancy; R13/
// R18 register-prefetch attempts failed) is hidden by thread-level
// parallelism instead.
// h writes: u64 agent-scope atomic store (R19-proven coherent, no RMW);
// h reads: plain loads, fresh via depth-32 ring capacity eviction.
// KPAD 2056/1544 (16B-aligned rows). Lead cap 4 (mir1 >= s-3).
__global__ void __launch_bounds__(256, 2) lstm_persistent(
    const unsigned short* __restrict__ xb,
    const unsigned short* __restrict__ w0t,
    const unsigned short* __restrict__ w1t,
    const float* __restrict__ b0v, const float* __restrict__ b1v,
    unsigned short* __restrict__ ring0, unsigned short* __restrict__ ring1,
    unsigned* __restrict__ bar,
    float* __restrict__ out)
{
  extern __shared__ unsigned short lds[];

  const int wg    = blockIdx.x;
  const int group = wg >> 8;       // 0: layer0 (blocks 0-255), 1: layer1
  const int wgl   = wg & 255;
  const int hu0   = wgl * 4;       // 4 units per block
  const int tid   = threadIdx.x;
  const int lane  = tid & 63;
  const int wid   = tid >> 6;
  const int c16   = lane & 15;
  const int row4  = lane >> 4;     // this lane's unit-local index (0..3)
  const int bb    = wid * 16 + c16; // this lane's batch

  const int K    = group ? 2048 : 1536;
  const int KPAD = group ? 2056 : 1544;

  { // stage weight slice global -> LDS: rows wgl*16 .. wgl*16+15, direct copy
    const unsigned short* wsrc = (group ? w1t : w0t) + (size_t)(wgl * 16) * K;
    const int kv = K >> 3;
    for (int c = tid; c < 16 * kv; c += 256) {
      int r = c / kv, q = c - r * kv;
      *(short8*)&lds[r * KPAD + q * 8] = *(const short8*)&wsrc[(size_t)r * K + q * 8];
    }
  }
  __syncthreads();

  // acc reg j = gate j of unit (hu0 + row4): LDS row r = ul*4 + g,
  // C-row = row4*4 + j  ->  ul = row4, g = j.
  const float* bsrc = group ? b1v : b0v;
  float bias[4];
#pragma unroll
  for (int j = 0; j < 4; ++j) bias[j] = bsrc[j * 1024 + hu0 + row4];

  const int a0b = c16 * KPAD + 8 * row4;

  const int lofs = (bb << 10) + 8 * row4;              // read offset within a slot
  const unsigned short* x_cur = xb + ((size_t)bb << 18) + 8 * row4;  // +512/step
  // u64 write covers units hu0..hu0+3 of batch bb (8B, done by row4==0 lane)
  unsigned short* rwb = (group ? ring1 : ring0) + (bb << 10) + hu0;
  float* out_base = out + ((size_t)bb << 19) + hu0 + row4;

  const int grp = wgl >> 4;                            // group within layer (0..15)
  unsigned* arrw  = bar + (group ? ARR1(grp) : ARR0(grp));
  unsigned* rootw = bar + (group ? ROOT1 : ROOT0);
  unsigned long long* pollw =
      (unsigned long long*)(bar + (group ? POLL1(grp) : POLL0(grp)));

  float cst = 0.0f;

  auto compute_episode = [&](int s) {
    const int t = group ? (s - 1) : s;

    f32x4 acc0 = { bias[0], bias[1], bias[2], bias[3] };

    const unsigned short* h0rd = ring0 + ((s - 1) & 31) * SLOT_ELEMS + lofs;  // h0[s-1]
    if (group == 0) {
      lstm_step_mfma<2, 6>(a0b, x_cur, h0rd, acc0);
      x_cur += 512;
    } else {
      const unsigned short* h1rd = ring1 + ((s - 2) & 31) * SLOT_ELEMS + lofs; // h1[t-1]
      lstm_step_mfma<4, 8>(a0b, h0rd, h1rd, acc0);
    }

    float iv = sigm(acc0[0]), fv = sigm(acc0[1]);
    float gv = tanhf(acc0[2]), ov = sigm(acc0[3]);
    cst = fv * cst + iv * gv;
    float hv = ov * tanhf(cst);

    // h write: pack 4 lanes' (row4=0..3) bf16 into one u64 agent-scope
    // atomic store (write-through to coherence point; R19-proven).
    unsigned hp = (unsigned)f2bf(hv);
    unsigned lo = hp | (__shfl_down(hp, 16) << 16);        // units +0,+1 (valid row4 0)
    unsigned hi = __shfl_down(lo, 32);                     // units +2,+3
    if (row4 == 0) {
      unsigned long long pk = (unsigned long long)lo | ((unsigned long long)hi << 32);
      unsigned long long* dst = (unsigned long long*)(rwb + (t & 31) * SLOT_ELEMS);
      __hip_atomic_store(dst, pk, __ATOMIC_RELAXED, __HIP_MEMORY_SCOPE_AGENT);
    }
    if (group) out_base[(size_t)t << 10] = hv;   // plain; flushed at dispatch end
  };

  for (int s = 0; s < 512; ++s) {
    const bool active = group ? (s >= 1) : true;
    if (active) compute_episode(s);

    // ---- per-layer two-level barrier (episode s), packed poll ----
    __syncthreads();   // drains vmem: this block's h-stores at coherence point
    if (tid == 0) {
      unsigned old = __hip_atomic_fetch_add(arrw, 1u, __ATOMIC_RELAXED, __HIP_MEMORY_SCOPE_AGENT);
      if (old == (unsigned)(16 * s + 15)) {                 // group complete
        unsigned old2 = __hip_atomic_fetch_add(rootw, 1u, __ATOMIC_RELAXED, __HIP_MEMORY_SCOPE_AGENT);
        if (old2 == (unsigned)(16 * s + 15)) {              // layer's last arriver
#pragma unroll
          for (int g2 = 0; g2 < 16; ++g2) {
            (void)__hip_atomic_exchange(bar + (group ? POLL1(g2) : POLL0(g2)), (unsigned)(s + 1),
                                        __ATOMIC_RELAXED, __HIP_MEMORY_SCOPE_AGENT);
            (void)__hip_atomic_exchange(bar + (group ? POLL0(g2) : POLL1(g2)) + 1, (unsigned)(s + 1),
                                        __ATOMIC_RELAXED, __HIP_MEMORY_SCOPE_AGENT);
          }
        }
      }
      const int own_tgt = s + 1;
      const int mir_tgt = group ? (s + 1) : (s - 3);        // L1: h0[s] ready; L0: lead cap 4
      for (;;) {
        unsigned long long v = __hip_atomic_load(pollw, __ATOMIC_RELAXED, __HIP_MEMORY_SCOPE_AGENT);
        int rel = (int)(unsigned)v;
        int mir = (int)(unsigned)(v >> 32);
        if (rel >= own_tgt && mir >= mir_tgt) break;
        __builtin_amdgcn_s_sleep(1);
      }
    }
    __syncthreads();
  }
  // L1 final episode (t=511): h0[511] guaranteed by s=511 exit (mir0 >= 512).
  if (group) compute_episode(512);
}

extern "C" void kernel_launch(void* const* d_in, const int* in_sizes, int n_in,
                              void* d_out, int out_size, void* d_ws, size_t ws_size,
                              hipStream_t stream) {
  const float* x   = (const float*)d_in[0];
  const float* Wx0 = (const float*)d_in[1];
  const float* Wh0 = (const float*)d_in[2];
  const float* b0  = (const float*)d_in[3];
  const float* Wx1 = (const float*)d_in[4];
  const float* Wh1 = (const float*)d_in[5];
  const float* b1  = (const float*)d_in[6];
  float* outp = (float*)d_out;

  char* ws = (char*)d_ws;
  unsigned short* xbp   = (unsigned short*)(ws + WS_XB);
  unsigned short* w0tp  = (unsigned short*)(ws + WS_W0T);
  unsigned short* w1tp  = (unsigned short*)(ws + WS_W1T);
  unsigned short* ring0 = (unsigned short*)(ws + WS_RING0);
  unsigned short* ring1 = (unsigned short*)(ws + WS_RING1);
  unsigned*       barp  = (unsigned*)(ws + WS_BAR);

  // prep
  sentinel_kernel<<<dim3(1), dim3(1), 0, stream>>>(outp);
  convert_x_kernel<<<dim3(16384), dim3(256), 0, stream>>>(x, xbp);
  transpose_weights_kernel<<<dim3(48, 128), dim3(32, 8), 0, stream>>>(Wx0, Wh0, w0tp, 512, 1536);
  transpose_weights_kernel<<<dim3(64, 128), dim3(32, 8), 0, stream>>>(Wx1, Wh1, w1tp, 1024, 2048);
  // zero the t=-1 slots (slot 31 of each ring) + barrier words
  hipMemsetAsync(ring0 + 31 * SLOT_ELEMS, 0, SLOT_BYTES, stream);
  hipMemsetAsync(ring1 + 31 * SLOT_ELEMS, 0, SLOT_BYTES, stream);
  hipMemsetAsync(barp, 0, 8192, stream);

  // persistent fused kernel, 512 blocks (2/CU); prefer cooperative launch,
  // fall back to a plain launch (512 blocks x 2/CU co-resident on 256 CUs).
  void* kargs[] = { (void*)&xbp, (void*)&w0tp, (void*)&w1tp, (void*)&b0, (void*)&b1,
                    (void*)&ring0, (void*)&ring1, (void*)&barp, (void*)&outp };
  hipError_t e = hipLaunchCooperativeKernel((void*)lstm_persistent, dim3(512), dim3(256),
                                            kargs, 16 * 2056 * 2 /* 65,792 B LDS */, stream);
  if (e != hipSuccess) {
    lstm_persistent<<<dim3(512), dim3(256), 16 * 2056 * 2, stream>>>(
        xbp, w0tp, w1tp, b0, b1, ring0, ring1, barp, outp);
  }
}

// Round 21
// 5104.170 us; speedup vs baseline: 1.4820x; 1.4820x over previous
//
#include <hip/hip_runtime.h>

typedef __attribute__((ext_vector_type(8))) short short8;
typedef __attribute__((ext_vector_type(4))) float f32x4;

// Workspace layout (bytes)
#define WS_XB     0ull          // x in bf16: [64][512][512]            33,554,432 B
#define WS_W0T    33554432ull   // layer0 weights^T fused: [4096][1536] 12,582,912 B
#define WS_W1T    46137344ull   // layer1 weights^T fused: [4096][2048] 16,777,216 B
#define WS_RING0  62914560ull   // h0 ring: [32][64][1024] bf16           4,194,304 B
#define WS_RING1  67108864ull   // h1 ring: [32][64][1024] bf16           4,194,304 B
#define WS_BAR    71303168ull   // barrier words (<=4096 B used)
#define SLOT_ELEMS 65536        // 64 batches x 1024 units per ring slot
#define SLOT_BYTES 131072

// R16/R19 barrier layout (best measured). Laws: <=16 same-line RMWs AND
// <=2 RMW-writers per poll line per episode; single-u64-load polls;
// fan-out across lines.
#define ARR0(g)  ((g) * 16)
#define ARR1(g)  (128 + (g) * 16)
#define ROOT0    256
#define ROOT1    272
#define POLL0(g) (288 + (g) * 16)
#define POLL1(g) (416 + (g) * 16)

__device__ __forceinline__ unsigned short f2bf(float f) {
  unsigned u = __float_as_uint(f);
  u += 0x7FFFu + ((u >> 16) & 1u);   // round-to-nearest-even
  return (unsigned short)(u >> 16);
}

__device__ __forceinline__ float sigm(float x) { return 1.0f / (1.0f + __expf(-x)); }

// ---- sentinel: "persistent kernel never ran" (absmax ~1e6) marker ----
__global__ void sentinel_kernel(float* out) { out[0] = 1.0e6f; }

// ---- prep: fp32 -> bf16 copy of x (4 elems/thread) ----
__global__ void convert_x_kernel(const float* __restrict__ x, unsigned short* __restrict__ xb) {
  int i = blockIdx.x * 256 + threadIdx.x;
  const float4 v = ((const float4*)x)[i];
  unsigned long long pack = (unsigned long long)f2bf(v.x)
                          | ((unsigned long long)f2bf(v.y) << 16)
                          | ((unsigned long long)f2bf(v.z) << 32)
                          | ((unsigned long long)f2bf(v.w) << 48);
  ((unsigned long long*)xb)[i] = pack;
}

// ---- prep: transpose [K][4096] fp32 (Wx stacked over Wh) -> [4096 perm][Ktot] bf16 ----
__global__ void transpose_weights_kernel(const float* __restrict__ wx, const float* __restrict__ wh,
                                         unsigned short* __restrict__ dst, int Kx, int Ktot) {
  __shared__ float tile[32][33];
  const int k0 = blockIdx.x * 32, n0 = blockIdx.y * 32;
  const int tx = threadIdx.x, ty = threadIdx.y;
#pragma unroll
  for (int i = 0; i < 4; ++i) {
    int k = k0 + ty + i * 8;
    tile[ty + i * 8][tx] = (k < Kx) ? wx[(size_t)k * 4096 + n0 + tx]
                                    : wh[(size_t)(k - Kx) * 4096 + n0 + tx];
  }
  __syncthreads();
#pragma unroll
  for (int i = 0; i < 4; ++i) {
    int n = n0 + ty + i * 8;
    int r = (n & 1023) * 4 + (n >> 10);
    dst[(size_t)r * Ktot + k0 + tx] = f2bf(tile[tx][ty + i * 8]);
  }
}

// ---- per-step MFMA micro-kernel: 6-SLOT pinned pipeline ----
// R19 had 4 slots (2 exposed MALL RTTs for L1's 8-block chain). 6 slots:
// L0 (NBLK=6) issues ALL blocks upfront, zero refills; L1 (NBLK=8) issues 6
// upfront + 2 refills, each covered by 5 computes -> ~1 exposed RTT.
// Pinned with sched_barrier(0) (R14 lesson: verify via VGPR ~230; 96 = void).
template<int N1, int NBLK>
__device__ __forceinline__ void lstm_step_mfma(int a0b, int a1b,
    const unsigned short* __restrict__ r1p, const unsigned short* __restrict__ r2p,
    f32x4& acc0, f32x4& acc1)
{
  extern __shared__ unsigned short lds[];
  short8 buf[6][8];

  auto loadB = [&](int slot, int blk) {
    const unsigned short* p = (blk < N1) ? (r1p + blk * 256) : (r2p + (blk - N1) * 256);
#pragma unroll
    for (int j = 0; j < 8; ++j) buf[slot][j] = *(const short8*)(p + j * 32);
  };
  auto compute8 = [&](int slot, int kg) {
#pragma unroll
    for (int j = 0; j < 8; ++j) {
      const int ko = kg + j * 32;
      short8 a0 = *(const short8*)&lds[a0b + ko];
      short8 a1 = *(const short8*)&lds[a1b + ko];
      acc0 = __builtin_amdgcn_mfma_f32_16x16x32_bf16(a0, buf[slot][j], acc0, 0, 0, 0);
      acc1 = __builtin_amdgcn_mfma_f32_16x16x32_bf16(a1, buf[slot][j], acc1, 0, 0, 0);
    }
  };

  loadB(0, 0); loadB(1, 1); loadB(2, 2); loadB(3, 3); loadB(4, 4); loadB(5, 5);
  __builtin_amdgcn_sched_barrier(0);            // all 6 issued before any compute
#pragma unroll
  for (int bp = 0; bp < NBLK; ++bp) {
    const int slot = bp % 6;
    compute8(slot, bp * 256);                   // consume block bp
    if (bp + 6 < NBLK) {                        // refill (L1 only: blocks 6,7)
      loadB(slot, bp + 6);
      __builtin_amdgcn_sched_barrier(0);        // refill may not sink
    }
  }
}

// ---- persistent fused 2-layer LSTM ----
// 256 WGs (1/CU). WGs [0,128): layer0; [128,256): layer1.
// R19 structure (best: 4,859us) + 6-slot pipeline + pure-spin polls
// (s_sleep removed: ~64cy x ~4 detect points off the release chain; 16
// pollers/line is the proven-safe contention level).
// h writes: u64 agent-scope atomic store (R19: coherent, no RMW).
// h reads: plain loads, fresh via depth-32 ring capacity eviction.
// KPAD 2056/1544 (16B-aligned LDS rows; 2-way bank aliasing free).
// Split per-layer barrier, lead cap 4 (mir1 >= s-3).
__global__ void __launch_bounds__(256, 1) lstm_persistent(
    const unsigned short* __restrict__ xb,
    const unsigned short* __restrict__ w0t,
    const unsigned short* __restrict__ w1t,
    const float* __restrict__ b0v, const float* __restrict__ b1v,
    unsigned short* __restrict__ ring0, unsigned short* __restrict__ ring1,
    unsigned* __restrict__ bar,
    float* __restrict__ out)
{
  extern __shared__ unsigned short lds[];

  const int wg    = blockIdx.x;
  const int group = wg >> 7;       // 0: layer0, 1: layer1
  const int wgl   = wg & 127;
  const int hu0   = wgl * 8;
  const int tid   = threadIdx.x;
  const int lane  = tid & 63;
  const int wid   = tid >> 6;
  const int c16   = lane & 15;
  const int row4  = lane >> 4;
  const int bb    = wid * 16 + c16; // this lane's batch

  const int K    = group ? 2048 : 1536;
  const int KPAD = group ? 2056 : 1544;

  { // stage weight slice global -> LDS, permuted: LDS row r <- slice row
    // src(r) = 8*((r&15)>>2) + 4*(r>>4) + (r&3)  (tile0 even-of-pair, tile1 odd)
    const unsigned short* wsrc = (group ? w1t : w0t) + (size_t)(wgl * 32) * K;
    const int kv = K >> 3;
    for (int c = tid; c < 32 * kv; c += 256) {
      int r = c / kv, q = c - r * kv;
      int srcr = 8 * ((r & 15) >> 2) + 4 * (r >> 4) + (r & 3);
      *(short8*)&lds[r * KPAD + q * 8] = *(const short8*)&wsrc[(size_t)srcr * K + q * 8];
    }
  }
  __syncthreads();

  const float* bsrc = group ? b1v : b0v;
  float bias0[4], bias1[4];
#pragma unroll
  for (int j = 0; j < 4; ++j) {
    bias0[j] = bsrc[j * 1024 + hu0 + 2 * row4];       // even unit of pair
    bias1[j] = bsrc[j * 1024 + hu0 + 2 * row4 + 1];   // odd unit of pair
  }

  const int a0b = c16 * KPAD + 8 * row4;
  const int a1b = a0b + 16 * KPAD;

  const int lofs = (bb << 10) + 8 * row4;              // read offset within a slot
  const unsigned short* x_cur = xb + ((size_t)bb << 18) + 8 * row4;  // +512/step
  unsigned* rwb0 = (unsigned*)(group ? ring1 : ring0) + (((bb << 10) + hu0) >> 1);
  float* out_base = out + ((size_t)bb << 19) + hu0 + 2 * row4;

  const int grp = wgl >> 4;                            // group within layer (0..7)
  unsigned* arrw  = bar + (group ? ARR1(grp) : ARR0(grp));
  unsigned* rootw = bar + (group ? ROOT1 : ROOT0);
  unsigned long long* pollw =
      (unsigned long long*)(bar + (group ? POLL1(grp) : POLL0(grp)));

  float cst0 = 0.0f, cst1 = 0.0f;

  auto compute_episode = [&](int s) {
    const int t = group ? (s - 1) : s;

    f32x4 acc0 = { bias0[0], bias0[1], bias0[2], bias0[3] };
    f32x4 acc1 = { bias1[0], bias1[1], bias1[2], bias1[3] };

    const unsigned short* h0rd = ring0 + ((s - 1) & 31) * SLOT_ELEMS + lofs;  // h0[s-1]
    if (group == 0) {
      lstm_step_mfma<2, 6>(a0b, a1b, x_cur, h0rd, acc0, acc1);
      x_cur += 512;
    } else {
      const unsigned short* h1rd = ring1 + ((s - 2) & 31) * SLOT_ELEMS + lofs; // h1[t-1]
      lstm_step_mfma<4, 8>(a0b, a1b, h0rd, h1rd, acc0, acc1);
    }

    float hv0, hv1;
    {
      float iv = sigm(acc0[0]), fv = sigm(acc0[1]);
      float gv = tanhf(acc0[2]), ov = sigm(acc0[3]);
      cst0 = fv * cst0 + iv * gv;
      hv0 = ov * tanhf(cst0);
    }
    {
      float iv = sigm(acc1[0]), fv = sigm(acc1[1]);
      float gv = tanhf(acc1[2]), ov = sigm(acc1[3]);
      cst1 = fv * cst1 + iv * gv;
      hv1 = ov * tanhf(cst1);
    }
    // h write: u64 agent-scope ATOMIC STORE (write-through, no RMW).
    unsigned hp  = (unsigned)f2bf(hv0) | ((unsigned)f2bf(hv1) << 16);
    unsigned hpo = __shfl_down(hp, 16);                // partner lane (row4+1)
    if ((row4 & 1) == 0) {
      unsigned long long pk = (unsigned long long)hp | ((unsigned long long)hpo << 32);
      unsigned long long* dst = (unsigned long long*)(rwb0 + (t & 31) * (SLOT_ELEMS / 2) + row4);
      __hip_atomic_store(dst, pk, __ATOMIC_RELAXED, __HIP_MEMORY_SCOPE_AGENT);
    }
    if (group) {
      float2 o2; o2.x = hv0; o2.y = hv1;
      *(float2*)(out_base + ((size_t)t << 10)) = o2;   // plain; flushed at dispatch end
    }
  };

  for (int s = 0; s < 512; ++s) {
    const bool active = group ? (s >= 1) : true;
    if (active) compute_episode(s);

    // ---- split per-layer barrier (episode s), pure-spin polls ----
    __syncthreads();   // drains vmem: this block's h-stores at coherence point
    if (tid == 0) {
      unsigned old = __hip_atomic_fetch_add(arrw, 1u, __ATOMIC_RELAXED, __HIP_MEMORY_SCOPE_AGENT);
      if (old == (unsigned)(16 * s + 15)) {                 // group complete
        unsigned old2 = __hip_atomic_fetch_add(rootw, 1u, __ATOMIC_RELAXED, __HIP_MEMORY_SCOPE_AGENT);
        if (old2 == (unsigned)(8 * s + 7)) {                // layer's last arriver
#pragma unroll
          for (int g2 = 0; g2 < 8; ++g2) {
            (void)__hip_atomic_exchange(bar + (group ? POLL1(g2) : POLL0(g2)), (unsigned)(s + 1),
                                        __ATOMIC_RELAXED, __HIP_MEMORY_SCOPE_AGENT);
            (void)__hip_atomic_exchange(bar + (group ? POLL0(g2) : POLL1(g2)) + 1, (unsigned)(s + 1),
                                        __ATOMIC_RELAXED, __HIP_MEMORY_SCOPE_AGENT);
          }
        }
      }
      const int own_tgt = s + 1;
      const int mir_tgt = group ? (s + 1) : (s - 3);        // L1: h0[s] ready; L0: lead cap 4
      for (;;) {                                            // pure spin (no s_sleep)
        unsigned long long v = __hip_atomic_load(pollw, __ATOMIC_RELAXED, __HIP_MEMORY_SCOPE_AGENT);
        int rel = (int)(unsigned)v;
        int mir = (int)(unsigned)(v >> 32);
        if (rel >= own_tgt && mir >= mir_tgt) break;
      }
    }
    __syncthreads();
  }
  // L1 final episode (t=511): h0[511] guaranteed by s=511 exit (mir0 >= 512).
  if (group) compute_episode(512);
}

extern "C" void kernel_launch(void* const* d_in, const int* in_sizes, int n_in,
                              void* d_out, int out_size, void* d_ws, size_t ws_size,
                              hipStream_t stream) {
  const float* x   = (const float*)d_in[0];
  const float* Wx0 = (const float*)d_in[1];
  const float* Wh0 = (const float*)d_in[2];
  const float* b0  = (const float*)d_in[3];
  const float* Wx1 = (const float*)d_in[4];
  const float* Wh1 = (const float*)d_in[5];
  const float* b1  = (const float*)d_in[6];
  float* outp = (float*)d_out;

  char* ws = (char*)d_ws;
  unsigned short* xbp   = (unsigned short*)(ws + WS_XB);
  unsigned short* w0tp  = (unsigned short*)(ws + WS_W0T);
  unsigned short* w1tp  = (unsigned short*)(ws + WS_W1T);
  unsigned short* ring0 = (unsigned short*)(ws + WS_RING0);
  unsigned short* ring1 = (unsigned short*)(ws + WS_RING1);
  unsigned*       barp  = (unsigned*)(ws + WS_BAR);

  // prep
  sentinel_kernel<<<dim3(1), dim3(1), 0, stream>>>(outp);
  convert_x_kernel<<<dim3(16384), dim3(256), 0, stream>>>(x, xbp);
  transpose_weights_kernel<<<dim3(48, 128), dim3(32, 8), 0, stream>>>(Wx0, Wh0, w0tp, 512, 1536);
  transpose_weights_kernel<<<dim3(64, 128), dim3(32, 8), 0, stream>>>(Wx1, Wh1, w1tp, 1024, 2048);
  // zero the t=-1 slots (slot 31 of each ring) + barrier words
  hipMemsetAsync(ring0 + 31 * SLOT_ELEMS, 0, SLOT_BYTES, stream);
  hipMemsetAsync(ring1 + 31 * SLOT_ELEMS, 0, SLOT_BYTES, stream);
  hipMemsetAsync(barp, 0, 4096, stream);

  // persistent fused kernel; prefer cooperative launch, fall back to a plain
  // launch (256 blocks x 1 block/CU is co-resident on 256 CUs) if it fails.
  void* kargs[] = { (void*)&xbp, (void*)&w0tp, (void*)&w1tp, (void*)&b0, (void*)&b1,
                    (void*)&ring0, (void*)&ring1, (void*)&barp, (void*)&outp };
  hipError_t e = hipLaunchCooperativeKernel((void*)lstm_persistent, dim3(256), dim3(256),
                                            kargs, 32 * 2056 * 2 /* 131,584 B LDS */, stream);
  if (e != hipSuccess) {
    lstm_persistent<<<dim3(256), dim3(256), 32 * 2056 * 2, stream>>>(
        xbp, w0tp, w1tp, b0, b1, ring0, ring1, barp, outp);
  }
}

// Round 22
// 4856.951 us; speedup vs baseline: 1.5574x; 1.0509x over previous
//
#include <hip/hip_runtime.h>

typedef __attribute__((ext_vector_type(8))) short short8;
typedef __attribute__((ext_vector_type(4))) float f32x4;

// Workspace layout (bytes)
#define WS_XB     0ull          // x in bf16: [64][512][512]            33,554,432 B
#define WS_W0T    33554432ull   // layer0 weights^T fused: [4096][1536] 12,582,912 B
#define WS_W1T    46137344ull   // layer1 weights^T fused: [4096][2048] 16,777,216 B
#define WS_RING0  62914560ull   // h0 ring: [32][64][1024] bf16           4,194,304 B
#define WS_RING1  67108864ull   // h1 ring: [32][64][1024] bf16           4,194,304 B
#define WS_BAR    71303168ull   // barrier words (<=4096 B used)
#define SLOT_ELEMS 65536        // 64 batches x 1024 units per ring slot
#define SLOT_BYTES 131072

// R16/R19 barrier layout (best measured: 4,859us). Laws: <=16 same-line RMWs
// AND <=2 RMW-writers per poll line per episode; single-u64-load polls;
// fan-out across lines.
//   ARR0(g)=g*16, ARR1(g)=128+g*16, ROOT0=256, ROOT1=272
//   POLL0(g)=288+g*16: word0=rel0, word1=mir1   POLL1(g)=416+g*16: word0=rel1, word1=mir0
#define ARR0(g)  ((g) * 16)
#define ARR1(g)  (128 + (g) * 16)
#define ROOT0    256
#define ROOT1    272
#define POLL0(g) (288 + (g) * 16)
#define POLL1(g) (416 + (g) * 16)

__device__ __forceinline__ unsigned short f2bf(float f) {
  unsigned u = __float_as_uint(f);
  u += 0x7FFFu + ((u >> 16) & 1u);   // round-to-nearest-even
  return (unsigned short)(u >> 16);
}

__device__ __forceinline__ float sigm(float x) { return 1.0f / (1.0f + __expf(-x)); }

// ---- sentinel: "persistent kernel never ran" (absmax ~1e6) marker ----
__global__ void sentinel_kernel(float* out) { out[0] = 1.0e6f; }

// ---- prep: fp32 -> bf16 copy of x (4 elems/thread) ----
__global__ void convert_x_kernel(const float* __restrict__ x, unsigned short* __restrict__ xb) {
  int i = blockIdx.x * 256 + threadIdx.x;
  const float4 v = ((const float4*)x)[i];
  unsigned long long pack = (unsigned long long)f2bf(v.x)
                          | ((unsigned long long)f2bf(v.y) << 16)
                          | ((unsigned long long)f2bf(v.z) << 32)
                          | ((unsigned long long)f2bf(v.w) << 48);
  ((unsigned long long*)xb)[i] = pack;
}

// ---- prep: transpose [K][4096] fp32 (Wx stacked over Wh) -> [4096 perm][Ktot] bf16 ----
__global__ void transpose_weights_kernel(const float* __restrict__ wx, const float* __restrict__ wh,
                                         unsigned short* __restrict__ dst, int Kx, int Ktot) {
  __shared__ float tile[32][33];
  const int k0 = blockIdx.x * 32, n0 = blockIdx.y * 32;
  const int tx = threadIdx.x, ty = threadIdx.y;
#pragma unroll
  for (int i = 0; i < 4; ++i) {
    int k = k0 + ty + i * 8;
    tile[ty + i * 8][tx] = (k < Kx) ? wx[(size_t)k * 4096 + n0 + tx]
                                    : wh[(size_t)(k - Kx) * 4096 + n0 + tx];
  }
  __syncthreads();
#pragma unroll
  for (int i = 0; i < 4; ++i) {
    int n = n0 + ty + i * 8;
    int r = (n & 1023) * 4 + (n >> 10);
    dst[(size_t)r * Ktot + k0 + tx] = f2bf(tile[tx][ty + i * 8]);
  }
}

// ---- per-step MFMA micro-kernel: R8's pinned 4-slot body (VGPR ~96 gate) ----
template<int N1, int NBLK>
__device__ __forceinline__ void lstm_step_mfma(int a0b, int a1b,
    const unsigned short* __restrict__ r1p, const unsigned short* __restrict__ r2p,
    f32x4& acc0, f32x4& acc1)
{
  extern __shared__ unsigned short lds[];
  short8 buf[4][8];

  auto loadB = [&](int slot, int blk) {
    const unsigned short* p = (blk < N1) ? (r1p + blk * 256) : (r2p + (blk - N1) * 256);
#pragma unroll
    for (int j = 0; j < 8; ++j) buf[slot][j] = *(const short8*)(p + j * 32);
  };
  auto compute8 = [&](int slot, int kg) {
#pragma unroll
    for (int j = 0; j < 8; ++j) {
      const int ko = kg + j * 32;
      short8 a0 = *(const short8*)&lds[a0b + ko];
      short8 a1 = *(const short8*)&lds[a1b + ko];
      acc0 = __builtin_amdgcn_mfma_f32_16x16x32_bf16(a0, buf[slot][j], acc0, 0, 0, 0);
      acc1 = __builtin_amdgcn_mfma_f32_16x16x32_bf16(a1, buf[slot][j], acc1, 0, 0, 0);
    }
  };

  loadB(0, 0); loadB(1, 1); loadB(2, 2); loadB(3, 3);
  __builtin_amdgcn_sched_barrier(0);            // all 4 blocks issued before any compute
#pragma unroll
  for (int bp = 0; bp < NBLK; ++bp) {
    compute8(bp & 3, bp * 256);                 // consume block bp
    if (bp + 4 < NBLK) loadB(bp & 3, bp + 4);   // refill the freed slot
    __builtin_amdgcn_sched_barrier(0);          // refill may not sink into later iters
  }
}

// ---- persistent fused 2-layer LSTM (R19: measured optimum, 4,859us) ----
// 256 WGs (1/CU). WGs [0,128): layer0; [128,256): layer1.
// Split per-layer two-level barriers with packed poll lines; lead cap 4.
// h writes: u64 agent-scope atomic store (write-through to coherence point;
// R19 falsified the "only RMWs are coherent" model). h reads: plain loads,
// fresh via depth-32 ring capacity eviction. KPAD 2056/1544 (16B-aligned
// LDS rows -- R11/R12: stride must be a multiple of 8 elems; the 2.35e8
// SQ_LDS_BANK_CONFLICT is structural 2-way aliasing, free per m136).
// Structural ceiling: 512 serial cross-XCD exchange rounds x ~9.4us
// {~1.4 compute, ~2 exposed MALL RTTs, ~3 barrier chain, ~3 skew}; nine
// sync-attack axes (R9-R21) measured flat or negative against it.
__global__ void __launch_bounds__(256, 1) lstm_persistent(
    const unsigned short* __restrict__ xb,
    const unsigned short* __restrict__ w0t,
    const unsigned short* __restrict__ w1t,
    const float* __restrict__ b0v, const float* __restrict__ b1v,
    unsigned short* __restrict__ ring0, unsigned short* __restrict__ ring1,
    unsigned* __restrict__ bar,
    float* __restrict__ out)
{
  extern __shared__ unsigned short lds[];

  const int wg    = blockIdx.x;
  const int group = wg >> 7;       // 0: layer0, 1: layer1
  const int wgl   = wg & 127;
  const int hu0   = wgl * 8;
  const int tid   = threadIdx.x;
  const int lane  = tid & 63;
  const int wid   = tid >> 6;
  const int c16   = lane & 15;
  const int row4  = lane >> 4;
  const int bb    = wid * 16 + c16; // this lane's batch

  const int K    = group ? 2048 : 1536;
  const int KPAD = group ? 2056 : 1544;

  { // stage weight slice global -> LDS, permuted: LDS row r <- slice row
    // src(r) = 8*((r&15)>>2) + 4*(r>>4) + (r&3)  (tile0 even-of-pair, tile1 odd)
    const unsigned short* wsrc = (group ? w1t : w0t) + (size_t)(wgl * 32) * K;
    const int kv = K >> 3;
    for (int c = tid; c < 32 * kv; c += 256) {
      int r = c / kv, q = c - r * kv;
      int srcr = 8 * ((r & 15) >> 2) + 4 * (r >> 4) + (r & 3);
      *(short8*)&lds[r * KPAD + q * 8] = *(const short8*)&wsrc[(size_t)srcr * K + q * 8];
    }
  }
  __syncthreads();

  const float* bsrc = group ? b1v : b0v;
  float bias0[4], bias1[4];
#pragma unroll
  for (int j = 0; j < 4; ++j) {
    bias0[j] = bsrc[j * 1024 + hu0 + 2 * row4];       // even unit of pair
    bias1[j] = bsrc[j * 1024 + hu0 + 2 * row4 + 1];   // odd unit of pair
  }

  const int a0b = c16 * KPAD + 8 * row4;
  const int a1b = a0b + 16 * KPAD;

  const int lofs = (bb << 10) + 8 * row4;              // read offset within a slot
  const unsigned short* x_cur = xb + ((size_t)bb << 18) + 8 * row4;  // +512/step
  unsigned* rwb0 = (unsigned*)(group ? ring1 : ring0) + (((bb << 10) + hu0) >> 1);
  float* out_base = out + ((size_t)bb << 19) + hu0 + 2 * row4;

  const int grp = wgl >> 4;                            // group within layer (0..7)
  unsigned* arrw  = bar + (group ? ARR1(grp) : ARR0(grp));
  unsigned* rootw = bar + (group ? ROOT1 : ROOT0);
  unsigned long long* pollw =
      (unsigned long long*)(bar + (group ? POLL1(grp) : POLL0(grp)));

  float cst0 = 0.0f, cst1 = 0.0f;

  auto compute_episode = [&](int s) {
    const int t = group ? (s - 1) : s;

    f32x4 acc0 = { bias0[0], bias0[1], bias0[2], bias0[3] };
    f32x4 acc1 = { bias1[0], bias1[1], bias1[2], bias1[3] };

    const unsigned short* h0rd = ring0 + ((s - 1) & 31) * SLOT_ELEMS + lofs;  // h0[s-1]
    if (group == 0) {
      lstm_step_mfma<2, 6>(a0b, a1b, x_cur, h0rd, acc0, acc1);
      x_cur += 512;
    } else {
      const unsigned short* h1rd = ring1 + ((s - 2) & 31) * SLOT_ELEMS + lofs; // h1[t-1]
      lstm_step_mfma<4, 8>(a0b, a1b, h0rd, h1rd, acc0, acc1);
    }

    float hv0, hv1;
    {
      float iv = sigm(acc0[0]), fv = sigm(acc0[1]);
      float gv = tanhf(acc0[2]), ov = sigm(acc0[3]);
      cst0 = fv * cst0 + iv * gv;
      hv0 = ov * tanhf(cst0);
    }
    {
      float iv = sigm(acc1[0]), fv = sigm(acc1[1]);
      float gv = tanhf(acc1[2]), ov = sigm(acc1[3]);
      cst1 = fv * cst1 + iv * gv;
      hv1 = ov * tanhf(cst1);
    }
    // h write: u64 agent-scope ATOMIC STORE (write-through, no RMW).
    unsigned hp  = (unsigned)f2bf(hv0) | ((unsigned)f2bf(hv1) << 16);
    unsigned hpo = __shfl_down(hp, 16);                // partner lane (row4+1)
    if ((row4 & 1) == 0) {
      unsigned long long pk = (unsigned long long)hp | ((unsigned long long)hpo << 32);
      unsigned long long* dst = (unsigned long long*)(rwb0 + (t & 31) * (SLOT_ELEMS / 2) + row4);
      __hip_atomic_store(dst, pk, __ATOMIC_RELAXED, __HIP_MEMORY_SCOPE_AGENT);
    }
    if (group) {
      float2 o2; o2.x = hv0; o2.y = hv1;
      *(float2*)(out_base + ((size_t)t << 10)) = o2;   // plain; flushed at dispatch end
    }
  };

  for (int s = 0; s < 512; ++s) {
    const bool active = group ? (s >= 1) : true;
    if (active) compute_episode(s);

    // ---- R16 split per-layer barrier (episode s), packed poll ----
    __syncthreads();   // drains vmem: this block's h-stores at coherence point
    if (tid == 0) {
      unsigned old = __hip_atomic_fetch_add(arrw, 1u, __ATOMIC_RELAXED, __HIP_MEMORY_SCOPE_AGENT);
      if (old == (unsigned)(16 * s + 15)) {                 // group complete
        unsigned old2 = __hip_atomic_fetch_add(rootw, 1u, __ATOMIC_RELAXED, __HIP_MEMORY_SCOPE_AGENT);
        if (old2 == (unsigned)(8 * s + 7)) {                // layer's last arriver
#pragma unroll
          for (int g2 = 0; g2 < 8; ++g2) {
            (void)__hip_atomic_exchange(bar + (group ? POLL1(g2) : POLL0(g2)), (unsigned)(s + 1),
                                        __ATOMIC_RELAXED, __HIP_MEMORY_SCOPE_AGENT);
            (void)__hip_atomic_exchange(bar + (group ? POLL0(g2) : POLL1(g2)) + 1, (unsigned)(s + 1),
                                        __ATOMIC_RELAXED, __HIP_MEMORY_SCOPE_AGENT);
          }
        }
      }
      const int own_tgt = s + 1;
      const int mir_tgt = group ? (s + 1) : (s - 3);        // L1: h0[s] ready; L0: lead cap 4
      for (;;) {
        unsigned long long v = __hip_atomic_load(pollw, __ATOMIC_RELAXED, __HIP_MEMORY_SCOPE_AGENT);
        int rel = (int)(unsigned)v;
        int mir = (int)(unsigned)(v >> 32);
        if (rel >= own_tgt && mir >= mir_tgt) break;
        __builtin_amdgcn_s_sleep(1);
      }
    }
    __syncthreads();
  }
  // L1 final episode (t=511): h0[511] guaranteed by s=511 exit (mir0 >= 512).
  if (group) compute_episode(512);
}

extern "C" void kernel_launch(void* const* d_in, const int* in_sizes, int n_in,
                              void* d_out, int out_size, void* d_ws, size_t ws_size,
                              hipStream_t stream) {
  const float* x   = (const float*)d_in[0];
  const float* Wx0 = (const float*)d_in[1];
  const float* Wh0 = (const float*)d_in[2];
  const float* b0  = (const float*)d_in[3];
  const float* Wx1 = (const float*)d_in[4];
  const float* Wh1 = (const float*)d_in[5];
  const float* b1  = (const float*)d_in[6];
  float* outp = (float*)d_out;

  char* ws = (char*)d_ws;
  unsigned short* xbp   = (unsigned short*)(ws + WS_XB);
  unsigned short* w0tp  = (unsigned short*)(ws + WS_W0T);
  unsigned short* w1tp  = (unsigned short*)(ws + WS_W1T);
  unsigned short* ring0 = (unsigned short*)(ws + WS_RING0);
  unsigned short* ring1 = (unsigned short*)(ws + WS_RING1);
  unsigned*       barp  = (unsigned*)(ws + WS_BAR);

  // prep
  sentinel_kernel<<<dim3(1), dim3(1), 0, stream>>>(outp);
  convert_x_kernel<<<dim3(16384), dim3(256), 0, stream>>>(x, xbp);
  transpose_weights_kernel<<<dim3(48, 128), dim3(32, 8), 0, stream>>>(Wx0, Wh0, w0tp, 512, 1536);
  transpose_weights_kernel<<<dim3(64, 128), dim3(32, 8), 0, stream>>>(Wx1, Wh1, w1tp, 1024, 2048);
  // zero the t=-1 slots (slot 31 of each ring) + barrier words
  hipMemsetAsync(ring0 + 31 * SLOT_ELEMS, 0, SLOT_BYTES, stream);
  hipMemsetAsync(ring1 + 31 * SLOT_ELEMS, 0, SLOT_BYTES, stream);
  hipMemsetAsync(barp, 0, 4096, stream);

  // persistent fused kernel; prefer cooperative launch, fall back to a plain
  // launch (256 blocks x 1 block/CU is co-resident on 256 CUs) if it fails.
  void* kargs[] = { (void*)&xbp, (void*)&w0tp, (void*)&w1tp, (void*)&b0, (void*)&b1,
                    (void*)&ring0, (void*)&ring1, (void*)&barp, (void*)&outp };
  hipError_t e = hipLaunchCooperativeKernel((void*)lstm_persistent, dim3(256), dim3(256),
                                            kargs, 32 * 2056 * 2 /* 131,584 B LDS */, stream);
  if (e != hipSuccess) {
    lstm_persistent<<<dim3(256), dim3(256), 32 * 2056 * 2, stream>>>(
        xbp, w0tp, w1tp, b0, b1, ring0, ring1, barp, outp);
  }
}